// Round 14
// baseline (40.085 us; speedup 1.0000x reference)
//
#include <hip/hip_runtime.h>
#include <hip/hip_fp16.h>
#include <string.h>

// Problem constants (SCALE=2, K=5, PATCH=3, STRIDE=1)
#define CY     64           // y channels
#define HY     80           // y spatial
#define HD     40           // yd spatial
#define SPD    (HD*HD)      // 1600
#define M1     78           // query patch grid dim
#define N1     38           // matched patch grid dim
#define M_TOT  (M1*M1)      // 6084
#define N_TOT  (N1*N1)      // 1444
#define KK     5
#define HS     160          // output spatial
#define EPSF   1e-5f
#define LP     33           // LDS row pitch (floats) for 32-col epilogue: 2-way max (free)

typedef float f32x2 __attribute__((ext_vector_type(2)));

__device__ __forceinline__ unsigned pkf16(float a, float b) {
    __half2 h = __floats2half2_rn(a, b);
    unsigned u; memcpy(&u, &h, 4); return u;
}
__device__ __forceinline__ f32x2 upk2(unsigned u) {
    __half2 h; memcpy(&h, &u, 4);
    float2 f = __half22float2(h);
    f32x2 r; r.x = f.x; r.y = f.y; return r;
}

// Fused pre-pass, partitioned by flat thread id (all parts independent):
//  A: yd -> ydW[sp][cc] = uint4{ f16x4 @ sp, f16x4 @ sp+1 }  (dup-pair layout)
//  B: zstP[n][cc] = pack(mu, 1/sd) over 36 elems
//  C: ystP[m][cc] = pack(mu, sd) over 9 elems
__global__ __launch_bounds__(256) void pre_kernel(const float* __restrict__ y,
                                                  const float* __restrict__ yd,
                                                  uint4* __restrict__ ydW,
                                                  unsigned* __restrict__ zstP,
                                                  unsigned* __restrict__ ystP) {
    int id = blockIdx.x * 256 + threadIdx.x;
    if (id < SPD * 64) {                       // ---- A: transpose (coalesced writes)
        int cc = id & 63, sp = id >> 6;
        const float* b0 = yd + (cc * 4) * SPD + sp;
        int d = (sp < SPD - 1) ? 1 : 0;        // clamp pad (never consumed)
        ydW[sp * 64 + cc] = make_uint4(pkf16(b0[0], b0[SPD]),
                                       pkf16(b0[2*SPD], b0[3*SPD]),
                                       pkf16(b0[d], b0[SPD+d]),
                                       pkf16(b0[2*SPD+d], b0[3*SPD+d]));
        return;
    }
    id -= SPD * 64;
    if (id < N_TOT * 64) {                     // ---- B: z-stats
        int n  = id % N_TOT;                   // lanes = consecutive n -> coalesced reads
        int cc = id / N_TOT;
        int ni = n / N1, nj = n - ni * N1;
        const float* base = yd + (cc * 4) * SPD + ni * HD + nj;
        float s = 0.f, sq = 0.f;
#pragma unroll
        for (int r = 0; r < 4; ++r)
#pragma unroll
            for (int i = 0; i < 3; ++i)
#pragma unroll
                for (int j = 0; j < 3; ++j) {
                    float v = base[r * SPD + i * HD + j];
                    s += v; sq += v * v;
                }
        float mu  = s * (1.f / 36.f);
        float var = (sq - 36.f * mu * mu) * (1.f / 35.f);
        zstP[n * 64 + cc] = pkf16(mu, rsqrtf(var + EPSF));
        return;
    }
    id -= N_TOT * 64;
    if (id >= CY * M_TOT) return;              // ---- C: y-stats
    int m  = id % M_TOT;                       // lanes = consecutive m -> coalesced reads
    int cc = id / M_TOT;
    int mi = m / M1, mj = m - mi * M1;
    const float* base = y + cc * (HY * HY) + mi * HY + mj;
    float s = 0.f, sq = 0.f;
#pragma unroll
    for (int i = 0; i < 3; ++i)
#pragma unroll
        for (int j = 0; j < 3; ++j) {
            float v = base[i * HY + j];
            s += v; sq += v * v;
        }
    float mu  = s * (1.f / 9.f);
    float var = (sq - 9.f * mu * mu) * (1.f / 8.f);
    ystP[m * 64 + cc] = pkf16(mu, sqrtf(var + EPSF));
}

// Main: block = 4 waves (256 thr); wave = FOUR x-adjacent 2x2 quads at one (k, quad-row y),
// lanes = cc. Patch union per wave = 3x6 -> 18 stat-pairs for 4 quads (-25% loads/px vs 2-quad).
// Per row: 6 patches, 8 yd issues (3x uint4 + ... dup-pair layout serves neighboring j's).
// Epilogue: LDS transpose over the block's 32-px X span -> full-line stores.
__global__ __launch_bounds__(256) void agg_kernel(
    const uint4* __restrict__ ydW, const unsigned* __restrict__ zstP,
    const unsigned* __restrict__ ystP, const int* __restrict__ idx,
    float* __restrict__ out)
{
    __shared__ float lds[128 * LP];            // 16,896 B

    int lane = threadIdx.x & 63;
    int w    = __builtin_amdgcn_readfirstlane(threadIdx.x >> 6);  // 0..3
    int bid  = blockIdx.x;                     // 0..1999
    int wg   = (bid & 7) * 250 + (bid >> 3);   // bijective XCD swizzle (2000 % 8 == 0)
    int k    = wg / 400;
    int rem  = wg - k * 400;
    int y    = rem / 5;                        // quad row 0..79
    int xsb  = rem - y * 5;                    // x super-block 0..4 (32 X pixels)
    int x0   = xsb * 16 + w * 4;               // first quad col of this wave (4 quads)

    f32x2 acc01[4] = {{0.f,0.f},{0.f,0.f},{0.f,0.f},{0.f,0.f}};  // dy0 (dx0,dx1) per quad
    f32x2 acc23[4] = {{0.f,0.f},{0.f,0.f},{0.f,0.f},{0.f,0.f}};  // dy1 per quad
    float bs[4]  = {0.f, 0.f, 0.f, 0.f};
    float inv[4] = {1.f/9.f, 1.f/9.f, 1.f/9.f, 1.f/9.f};

    auto serve = [&](int q, unsigned lo, unsigned hi, float a, float b) {
        f32x2 am; am.x = a; am.y = a;
        acc01[q] = __builtin_elementwise_fma(am, upk2(lo), acc01[q]);
        acc23[q] = __builtin_elementwise_fma(am, upk2(hi), acc23[q]);
        bs[q] += b;
    };

    if (y >= 2 && y <= M1 - 1 && x0 >= 2 && x0 + 3 <= M1 - 1) {
        int nn[18];                            // wave-uniform -> scalar loads
#pragma unroll
        for (int p = 0; p < 18; ++p) {
            int m = (y - 2 + p / 6) * M1 + (x0 - 2 + p % 6);
            nn[p] = idx[m * KK + k];
        }
#pragma unroll
        for (int r = 0; r < 3; ++r) {
            int roff  = (2 - r) * HD;
            int base_m = (y - 2 + r) * M1 + (x0 - 2);
            // 6 patches this row: stats + scalar spatial bases
            unsigned ysu[6], zsu[6];
            int sp[6];
#pragma unroll
            for (int c = 0; c < 6; ++c) {
                int n = nn[r * 6 + c];
                ysu[c] = ystP[(base_m + c) * 64 + lane];
                zsu[c] = zstP[n * 64 + lane];
                int ni = n / N1;
                sp[c]  = ni * HD + (n - ni * N1) + roff;
            }
            // yd loads (dup-pair): col c serves quads q in [c-2, c], j = q+2-c
            uint2 w0 = *(const uint2*)(ydW + (sp[0] + 2) * 64 + lane);
            uint4 u1 = ydW[(sp[1] + 1) * 64 + lane];
            uint4 u2 = ydW[(sp[2] + 0) * 64 + lane];
            uint2 w2 = *(const uint2*)(ydW + (sp[2] + 2) * 64 + lane);
            uint4 u3 = ydW[(sp[3] + 0) * 64 + lane];
            uint2 w3 = *(const uint2*)(ydW + (sp[3] + 2) * 64 + lane);
            uint4 u4 = ydW[(sp[4] + 0) * 64 + lane];
            uint2 w5 = *(const uint2*)(ydW + (sp[5] + 0) * 64 + lane);
            float aa[6], bb[6];
#pragma unroll
            for (int c = 0; c < 6; ++c) {
                f32x2 ys = upk2(ysu[c]), zs = upk2(zsu[c]);
                aa[c] = ys.y * zs.y;           // y_sd * inv_z_sd
                bb[c] = fmaf(-zs.x, aa[c], ys.x);
            }
            serve(0, w0.x, w0.y, aa[0], bb[0]);                       // c0: q0 j2
            serve(0, u1.x, u1.y, aa[1], bb[1]);                       // c1: q0 j1
            serve(1, u1.z, u1.w, aa[1], bb[1]);                       //     q1 j2
            serve(0, u2.x, u2.y, aa[2], bb[2]);                       // c2: q0 j0
            serve(1, u2.z, u2.w, aa[2], bb[2]);                       //     q1 j1
            serve(2, w2.x, w2.y, aa[2], bb[2]);                       //     q2 j2
            serve(1, u3.x, u3.y, aa[3], bb[3]);                       // c3: q1 j0
            serve(2, u3.z, u3.w, aa[3], bb[3]);                       //     q2 j1
            serve(3, w3.x, w3.y, aa[3], bb[3]);                       //     q3 j2
            serve(2, u4.x, u4.y, aa[4], bb[4]);                       // c4: q2 j0
            serve(3, u4.z, u4.w, aa[4], bb[4]);                       //     q3 j1
            serve(3, w5.x, w5.y, aa[5], bb[5]);                       // c5: q3 j0
        }
    } else {
#pragma unroll
        for (int q = 0; q < 4; ++q) {
            int x = x0 + q;
            int milo = max(0, y - 2), mihi = min(M1 - 1, y);
            int mjlo = max(0, x - 2), mjhi = min(M1 - 1, x);
            inv[q] = 1.f / (float)((mihi - milo + 1) * (mjhi - mjlo + 1));
            for (int mi = milo; mi <= mihi; ++mi)
                for (int mj = mjlo; mj <= mjhi; ++mj) {
                    int m = mi * M1 + mj;
                    int n = idx[m * KK + k];   // uniform -> s_load
                    f32x2 ys = upk2(ystP[m * 64 + lane]);
                    f32x2 zs = upk2(zstP[n * 64 + lane]);
                    float a = ys.y * zs.y;
                    float b = fmaf(-zs.x, a, ys.x);
                    int ni = n / N1;
                    int spq = ni * HD + (n - ni * N1) + (y - mi) * HD + (x - mj);
                    uint2 v = *(const uint2*)(ydW + spq * 64 + lane);
                    serve(q, v.x, v.y, a, b);
                }
        }
    }

    // Stage: row = dy*64 + cc (128 rows), col = w*8 + q*2 + dx (32 cols). Stride LP=33 -> free 2-way.
#pragma unroll
    for (int q = 0; q < 4; ++q) {
        float iv = inv[q];
        float bq = bs[q];
        int col = w * 8 + q * 2;
        lds[(0 * CY + lane) * LP + col]     = (acc01[q].x + bq) * iv;
        lds[(0 * CY + lane) * LP + col + 1] = (acc01[q].y + bq) * iv;
        lds[(1 * CY + lane) * LP + col]     = (acc23[q].x + bq) * iv;
        lds[(1 * CY + lane) * LP + col + 1] = (acc23[q].y + bq) * iv;
    }

    __syncthreads();

    // Drain: 128 rows x 32 cols; each 16-lane group writes a FULL 64B line.
    int rsel = lane >> 5, c = lane & 31;
    int X0 = xsb * 32, Y0 = 2 * y;
#pragma unroll
    for (int t = 0; t < 16; ++t) {
        int row = t * 8 + w * 2 + rsel;        // 0..127, each exactly once
        float v = lds[row * LP + c];
        int dy = row >> 6, cc = row & 63;
        out[((size_t)(k * CY + cc) * HS + (Y0 + dy)) * HS + X0 + c] = v;
    }
}

extern "C" void kernel_launch(void* const* d_in, const int* in_sizes, int n_in,
                              void* d_out, int out_size, void* d_ws, size_t ws_size,
                              hipStream_t stream) {
    const float* y   = (const float*)d_in[0];
    const float* yd  = (const float*)d_in[1];
    const int*   idx = (const int*)d_in[2];
    float* out = (float*)d_out;

    char* ws = (char*)d_ws;
    uint4*    ydW  = (uint4*)ws;                             // 1,638,400 B
    unsigned* zstP = (unsigned*)(ws + 1638400);              //   369,664 B
    unsigned* ystP = (unsigned*)(ws + 2008064);              // 1,557,504 B

    int pre_total = SPD * 64 + N_TOT * 64 + CY * M_TOT;      // 584,192 -> 2283 blocks
    pre_kernel<<<(pre_total + 255) / 256, 256, 0, stream>>>(y, yd, ydW, zstP, ystP);
    agg_kernel<<<KK * 400, 256, 0, stream>>>(ydW, zstP, ystP, idx, out);
}

// Round 15
// 35.636 us; speedup vs baseline: 1.1249x; 1.1249x over previous
//
#include <hip/hip_runtime.h>
#include <hip/hip_fp16.h>
#include <string.h>

// Problem constants (SCALE=2, K=5, PATCH=3, STRIDE=1)
#define CY     64           // y channels
#define HY     80           // y spatial
#define HD     40           // yd spatial
#define SPD    (HD*HD)      // 1600
#define M1     78           // query patch grid dim
#define N1     38           // matched patch grid dim
#define M_TOT  (M1*M1)      // 6084
#define N_TOT  (N1*N1)      // 1444
#define KK     5
#define HS     160          // output spatial
#define EPSF   1e-5f
#define LP     17           // LDS row pitch (floats) for 16-col epilogue: 2-way max (free)

typedef float f32x2 __attribute__((ext_vector_type(2)));

__device__ __forceinline__ unsigned pkf16(float a, float b) {
    __half2 h = __floats2half2_rn(a, b);
    unsigned u; memcpy(&u, &h, 4); return u;
}
__device__ __forceinline__ f32x2 upk2(unsigned u) {
    __half2 h; memcpy(&h, &u, 4);
    float2 f = __half22float2(h);
    f32x2 r; r.x = f.x; r.y = f.y; return r;
}

// Fused pre-pass, partitioned by flat thread id (all parts independent):
//  A: yd -> ydW[sp][cc] = uint4{ f16x4 @ sp, f16x4 @ sp+1 }  (dup-pair layout)
//  B: zstP[n][cc] = pack(mu, 1/sd) over 36 elems
//  C: ystP[m][cc] = pack(mu, sd) over 9 elems
__global__ __launch_bounds__(256) void pre_kernel(const float* __restrict__ y,
                                                  const float* __restrict__ yd,
                                                  uint4* __restrict__ ydW,
                                                  unsigned* __restrict__ zstP,
                                                  unsigned* __restrict__ ystP) {
    int id = blockIdx.x * 256 + threadIdx.x;
    if (id < SPD * 64) {                       // ---- A: transpose (coalesced writes)
        int cc = id & 63, sp = id >> 6;
        const float* b0 = yd + (cc * 4) * SPD + sp;
        int d = (sp < SPD - 1) ? 1 : 0;        // clamp pad (never consumed)
        ydW[sp * 64 + cc] = make_uint4(pkf16(b0[0], b0[SPD]),
                                       pkf16(b0[2*SPD], b0[3*SPD]),
                                       pkf16(b0[d], b0[SPD+d]),
                                       pkf16(b0[2*SPD+d], b0[3*SPD+d]));
        return;
    }
    id -= SPD * 64;
    if (id < N_TOT * 64) {                     // ---- B: z-stats
        int n  = id % N_TOT;                   // lanes = consecutive n -> coalesced reads
        int cc = id / N_TOT;
        int ni = n / N1, nj = n - ni * N1;
        const float* base = yd + (cc * 4) * SPD + ni * HD + nj;
        float s = 0.f, sq = 0.f;
#pragma unroll
        for (int r = 0; r < 4; ++r)
#pragma unroll
            for (int i = 0; i < 3; ++i)
#pragma unroll
                for (int j = 0; j < 3; ++j) {
                    float v = base[r * SPD + i * HD + j];
                    s += v; sq += v * v;
                }
        float mu  = s * (1.f / 36.f);
        float var = (sq - 36.f * mu * mu) * (1.f / 35.f);
        zstP[n * 64 + cc] = pkf16(mu, rsqrtf(var + EPSF));
        return;
    }
    id -= N_TOT * 64;
    if (id >= CY * M_TOT) return;              // ---- C: y-stats
    int m  = id % M_TOT;                       // lanes = consecutive m -> coalesced reads
    int cc = id / M_TOT;
    int mi = m / M1, mj = m - mi * M1;
    const float* base = y + cc * (HY * HY) + mi * HY + mj;
    float s = 0.f, sq = 0.f;
#pragma unroll
    for (int i = 0; i < 3; ++i)
#pragma unroll
        for (int j = 0; j < 3; ++j) {
            float v = base[i * HY + j];
            s += v; sq += v * v;
        }
    float mu  = s * (1.f / 9.f);
    float var = (sq - 9.f * mu * mu) * (1.f / 8.f);
    ystP[m * 64 + cc] = pkf16(mu, sqrtf(var + EPSF));
}

// Main: block = 4 waves (256 thr); wave = TWO x-adjacent 2x2 quads, lanes = cc.
// TWO TILES per block (y0 and y0+40, same k/xb), software-pipelined:
// both tiles' stat chains issued up front; B's yd loads prefetched before A's
// epilogue so the barrier drain absorbs B's latency; B computes stall-free.
// Epilogue per tile: LDS transpose over 16-px X span -> full-line nt stores.
__global__ __launch_bounds__(256) void agg_kernel(
    const uint4* __restrict__ ydW, const unsigned* __restrict__ zstP,
    const unsigned* __restrict__ ystP, const int* __restrict__ idx,
    float* __restrict__ out)
{
    __shared__ float lds[128 * LP];            // 8,704 B

    int lane = threadIdx.x & 63;
    int w    = __builtin_amdgcn_readfirstlane(threadIdx.x >> 6);  // 0..3
    int bid  = blockIdx.x;                     // 0..1999
    int wg   = (bid & 7) * 250 + (bid >> 3);   // bijective XCD swizzle (2000 % 8 == 0)
    int k    = wg / 400;
    int rem  = wg - k * 400;
    int y0   = rem / 10;                       // 0..39
    int xb   = rem - y0 * 10;                  // 0..9 (16 X pixels)
    int x0   = xb * 8 + w * 2;                 // quad A col; quad B = x0+1
    int yA   = y0, yB = y0 + 40;

    bool fx    = (x0 >= 2 && x0 <= M1 - 2);
    bool fastA = fx && (yA >= 2) && (yA <= M1 - 1);
    bool fastB = fx && (yB >= 2) && (yB <= M1 - 1);

    // ---- P1+P2: stat chains for BOTH tiles, all issued up front
    int nnA[12], nnB[12];
    unsigned ysuA[12], ysuB[12], zsuA[12], zsuB[12];
    if (fastA) {
#pragma unroll
        for (int p = 0; p < 12; ++p) {
            int m = (yA - 2 + (p >> 2)) * M1 + (x0 - 2 + (p & 3));
            nnA[p]  = idx[m * KK + k];         // uniform -> s_load
            ysuA[p] = ystP[m * 64 + lane];
        }
#pragma unroll
        for (int p = 0; p < 12; ++p) zsuA[p] = zstP[nnA[p] * 64 + lane];
    }
    if (fastB) {
#pragma unroll
        for (int p = 0; p < 12; ++p) {
            int m = (yB - 2 + (p >> 2)) * M1 + (x0 - 2 + (p & 3));
            nnB[p]  = idx[m * KK + k];
            ysuB[p] = ystP[m * 64 + lane];
        }
#pragma unroll
        for (int p = 0; p < 12; ++p) zsuB[p] = zstP[nnB[p] * 64 + lane];
    }

    auto serve = [&](f32x2& a01, f32x2& a23, float& bsum,
                     unsigned lo, unsigned hi, float a, float b) {
        f32x2 am; am.x = a; am.y = a;
        a01 = __builtin_elementwise_fma(am, upk2(lo), a01);
        a23 = __builtin_elementwise_fma(am, upk2(hi), a23);
        bsum += b;
    };

    auto slow_tile = [&](int yt, f32x2 a01[2], f32x2 a23[2], float bs[2],
                         float& i0, float& i1) {
#pragma unroll
        for (int q = 0; q < 2; ++q) {
            int x = x0 + q;
            int milo = max(0, yt - 2), mihi = min(M1 - 1, yt);
            int mjlo = max(0, x - 2), mjhi = min(M1 - 1, x);
            float iv = 1.f / (float)((mihi - milo + 1) * (mjhi - mjlo + 1));
            if (q == 0) i0 = iv; else i1 = iv;
            for (int mi = milo; mi <= mihi; ++mi)
                for (int mj = mjlo; mj <= mjhi; ++mj) {
                    int m = mi * M1 + mj;
                    int n = idx[m * KK + k];
                    f32x2 ys = upk2(ystP[m * 64 + lane]);
                    f32x2 zs = upk2(zstP[n * 64 + lane]);
                    float a = ys.y * zs.y;
                    float b = fmaf(-zs.x, a, ys.x);
                    int ni = n / N1;
                    int sp = ni * HD + (n - ni * N1) + (yt - mi) * HD + (x - mj);
                    uint2 v = *(const uint2*)(ydW + sp * 64 + lane);
                    if (q == 0) serve(a01[0], a23[0], bs[0], v.x, v.y, a, b);
                    else        serve(a01[1], a23[1], bs[1], v.x, v.y, a, b);
                }
        }
    };

    // ---- Tile A compute
    f32x2 accA01[2] = {{0.f,0.f},{0.f,0.f}};
    f32x2 accA23[2] = {{0.f,0.f},{0.f,0.f}};
    float bsA[2] = {0.f, 0.f};
    float invA0 = 1.f / 9.f, invA1 = 1.f / 9.f;
    if (fastA) {
        int spbA[12];
#pragma unroll
        for (int p = 0; p < 12; ++p) {
            int n = nnA[p], ni = n / N1;
            spbA[p] = ni * HD + (n - ni * N1);
        }
        uint2 Aw0[3], Aw3[3]; uint4 Au1[3], Au2[3];
#pragma unroll
        for (int r = 0; r < 3; ++r) {          // all 12 yd loads issued up front
            int roff = (2 - r) * HD;
            Aw0[r] = *(const uint2*)(ydW + (spbA[r*4+0] + roff + 2) * 64 + lane);
            Au1[r] = ydW[(spbA[r*4+1] + roff + 1) * 64 + lane];
            Au2[r] = ydW[(spbA[r*4+2] + roff + 0) * 64 + lane];
            Aw3[r] = *(const uint2*)(ydW + (spbA[r*4+3] + roff + 0) * 64 + lane);
        }
#pragma unroll
        for (int r = 0; r < 3; ++r) {
            float aa0, bb0, aa1, bb1, aa2, bb2, aa3, bb3;
            { f32x2 ys = upk2(ysuA[r*4+0]), zs = upk2(zsuA[r*4+0]);
              aa0 = ys.y * zs.y; bb0 = fmaf(-zs.x, aa0, ys.x); }
            { f32x2 ys = upk2(ysuA[r*4+1]), zs = upk2(zsuA[r*4+1]);
              aa1 = ys.y * zs.y; bb1 = fmaf(-zs.x, aa1, ys.x); }
            { f32x2 ys = upk2(ysuA[r*4+2]), zs = upk2(zsuA[r*4+2]);
              aa2 = ys.y * zs.y; bb2 = fmaf(-zs.x, aa2, ys.x); }
            { f32x2 ys = upk2(ysuA[r*4+3]), zs = upk2(zsuA[r*4+3]);
              aa3 = ys.y * zs.y; bb3 = fmaf(-zs.x, aa3, ys.x); }
            serve(accA01[0], accA23[0], bsA[0], Aw0[r].x, Aw0[r].y, aa0, bb0);
            serve(accA01[0], accA23[0], bsA[0], Au1[r].x, Au1[r].y, aa1, bb1);
            serve(accA01[1], accA23[1], bsA[1], Au1[r].z, Au1[r].w, aa1, bb1);
            serve(accA01[0], accA23[0], bsA[0], Au2[r].x, Au2[r].y, aa2, bb2);
            serve(accA01[1], accA23[1], bsA[1], Au2[r].z, Au2[r].w, aa2, bb2);
            serve(accA01[1], accA23[1], bsA[1], Aw3[r].x, Aw3[r].y, aa3, bb3);
        }
    } else {
        slow_tile(yA, accA01, accA23, bsA, invA0, invA1);
    }

    // ---- Prefetch tile B's yd loads (latency hides under A's epilogue barriers)
    uint2 Bw0[3], Bw3[3]; uint4 Bu1[3], Bu2[3];
    if (fastB) {
        int spbB[12];
#pragma unroll
        for (int p = 0; p < 12; ++p) {
            int n = nnB[p], ni = n / N1;
            spbB[p] = ni * HD + (n - ni * N1);
        }
#pragma unroll
        for (int r = 0; r < 3; ++r) {
            int roff = (2 - r) * HD;
            Bw0[r] = *(const uint2*)(ydW + (spbB[r*4+0] + roff + 2) * 64 + lane);
            Bu1[r] = ydW[(spbB[r*4+1] + roff + 1) * 64 + lane];
            Bu2[r] = ydW[(spbB[r*4+2] + roff + 0) * 64 + lane];
            Bw3[r] = *(const uint2*)(ydW + (spbB[r*4+3] + roff + 0) * 64 + lane);
        }
    }

    // ---- Epilogue A: stage -> sync -> full-line nt drain -> sync
    {
#pragma unroll
        for (int q = 0; q < 2; ++q) {
            float iv = q ? invA1 : invA0;
            float bq = bsA[q];
            int col = (w * 2 + q) * 2;
            lds[(0 * CY + lane) * LP + col]     = (accA01[q].x + bq) * iv;
            lds[(0 * CY + lane) * LP + col + 1] = (accA01[q].y + bq) * iv;
            lds[(1 * CY + lane) * LP + col]     = (accA23[q].x + bq) * iv;
            lds[(1 * CY + lane) * LP + col + 1] = (accA23[q].y + bq) * iv;
        }
        __syncthreads();
        int q = lane >> 4, xi = lane & 15;
        int X0 = xb * 16, Y0 = 2 * yA;
#pragma unroll
        for (int t = 0; t < 8; ++t) {
            int row = t * 16 + w * 4 + q;
            float v = lds[row * LP + xi];
            int dy = row >> 6, cc = row & 63;
            __builtin_nontemporal_store(v,
                out + (((size_t)(k * CY + cc) * HS + (Y0 + dy)) * HS + X0 + xi));
        }
        __syncthreads();
    }

    // ---- Tile B compute (loads already resident)
    f32x2 accB01[2] = {{0.f,0.f},{0.f,0.f}};
    f32x2 accB23[2] = {{0.f,0.f},{0.f,0.f}};
    float bsB[2] = {0.f, 0.f};
    float invB0 = 1.f / 9.f, invB1 = 1.f / 9.f;
    if (fastB) {
#pragma unroll
        for (int r = 0; r < 3; ++r) {
            float aa0, bb0, aa1, bb1, aa2, bb2, aa3, bb3;
            { f32x2 ys = upk2(ysuB[r*4+0]), zs = upk2(zsuB[r*4+0]);
              aa0 = ys.y * zs.y; bb0 = fmaf(-zs.x, aa0, ys.x); }
            { f32x2 ys = upk2(ysuB[r*4+1]), zs = upk2(zsuB[r*4+1]);
              aa1 = ys.y * zs.y; bb1 = fmaf(-zs.x, aa1, ys.x); }
            { f32x2 ys = upk2(ysuB[r*4+2]), zs = upk2(zsuB[r*4+2]);
              aa2 = ys.y * zs.y; bb2 = fmaf(-zs.x, aa2, ys.x); }
            { f32x2 ys = upk2(ysuB[r*4+3]), zs = upk2(zsuB[r*4+3]);
              aa3 = ys.y * zs.y; bb3 = fmaf(-zs.x, aa3, ys.x); }
            serve(accB01[0], accB23[0], bsB[0], Bw0[r].x, Bw0[r].y, aa0, bb0);
            serve(accB01[0], accB23[0], bsB[0], Bu1[r].x, Bu1[r].y, aa1, bb1);
            serve(accB01[1], accB23[1], bsB[1], Bu1[r].z, Bu1[r].w, aa1, bb1);
            serve(accB01[0], accB23[0], bsB[0], Bu2[r].x, Bu2[r].y, aa2, bb2);
            serve(accB01[1], accB23[1], bsB[1], Bu2[r].z, Bu2[r].w, aa2, bb2);
            serve(accB01[1], accB23[1], bsB[1], Bw3[r].x, Bw3[r].y, aa3, bb3);
        }
    } else {
        slow_tile(yB, accB01, accB23, bsB, invB0, invB1);
    }

    // ---- Epilogue B
    {
#pragma unroll
        for (int q = 0; q < 2; ++q) {
            float iv = q ? invB1 : invB0;
            float bq = bsB[q];
            int col = (w * 2 + q) * 2;
            lds[(0 * CY + lane) * LP + col]     = (accB01[q].x + bq) * iv;
            lds[(0 * CY + lane) * LP + col + 1] = (accB01[q].y + bq) * iv;
            lds[(1 * CY + lane) * LP + col]     = (accB23[q].x + bq) * iv;
            lds[(1 * CY + lane) * LP + col + 1] = (accB23[q].y + bq) * iv;
        }
        __syncthreads();
        int q = lane >> 4, xi = lane & 15;
        int X0 = xb * 16, Y0 = 2 * yB;
#pragma unroll
        for (int t = 0; t < 8; ++t) {
            int row = t * 16 + w * 4 + q;
            float v = lds[row * LP + xi];
            int dy = row >> 6, cc = row & 63;
            __builtin_nontemporal_store(v,
                out + (((size_t)(k * CY + cc) * HS + (Y0 + dy)) * HS + X0 + xi));
        }
    }
}

extern "C" void kernel_launch(void* const* d_in, const int* in_sizes, int n_in,
                              void* d_out, int out_size, void* d_ws, size_t ws_size,
                              hipStream_t stream) {
    const float* y   = (const float*)d_in[0];
    const float* yd  = (const float*)d_in[1];
    const int*   idx = (const int*)d_in[2];
    float* out = (float*)d_out;

    char* ws = (char*)d_ws;
    uint4*    ydW  = (uint4*)ws;                             // 1,638,400 B
    unsigned* zstP = (unsigned*)(ws + 1638400);              //   369,664 B
    unsigned* ystP = (unsigned*)(ws + 2008064);              // 1,557,504 B

    int pre_total = SPD * 64 + N_TOT * 64 + CY * M_TOT;      // 584,192 -> 2283 blocks
    pre_kernel<<<(pre_total + 255) / 256, 256, 0, stream>>>(y, yd, ydW, zstP, ystP);
    agg_kernel<<<KK * 400, 256, 0, stream>>>(ydW, zstP, ystP, idx, out);
}

// Round 16
// 34.115 us; speedup vs baseline: 1.1750x; 1.0446x over previous
//
#include <hip/hip_runtime.h>
#include <hip/hip_fp16.h>
#include <string.h>

// Problem constants (SCALE=2, K=5, PATCH=3, STRIDE=1)
#define CY     64           // y channels
#define HY     80           // y spatial
#define HD     40           // yd spatial
#define SPD    (HD*HD)      // 1600
#define M1     78           // query patch grid dim
#define N1     38           // matched patch grid dim
#define M_TOT  (M1*M1)      // 6084
#define N_TOT  (N1*N1)      // 1444
#define KK     5
#define HS     160          // output spatial
#define EPSF   1e-5f
#define LP     17           // LDS row pitch (floats) for 16-col epilogue: 2-way max (free)

typedef float f32x2 __attribute__((ext_vector_type(2)));

__device__ __forceinline__ unsigned pkf16(float a, float b) {
    __half2 h = __floats2half2_rn(a, b);
    unsigned u; memcpy(&u, &h, 4); return u;
}
__device__ __forceinline__ f32x2 upk2(unsigned u) {
    __half2 h; memcpy(&h, &u, 4);
    float2 f = __half22float2(h);
    f32x2 r; r.x = f.x; r.y = f.y; return r;
}

// Fused pre-pass, partitioned by flat thread id (all parts independent):
//  A: yd -> ydW[sp][cc] = uint4{ f16x4 @ sp, f16x4 @ sp+1 }  (dup-pair layout)
//  B: zstP[n][cc] = pack(mu, 1/sd) over 36 elems
//  C: ystP[m][cc] = pack(mu, sd) over 9 elems
__global__ __launch_bounds__(256) void pre_kernel(const float* __restrict__ y,
                                                  const float* __restrict__ yd,
                                                  uint4* __restrict__ ydW,
                                                  unsigned* __restrict__ zstP,
                                                  unsigned* __restrict__ ystP) {
    int id = blockIdx.x * 256 + threadIdx.x;
    if (id < SPD * 64) {                       // ---- A: transpose (coalesced writes)
        int cc = id & 63, sp = id >> 6;
        const float* b0 = yd + (cc * 4) * SPD + sp;
        int d = (sp < SPD - 1) ? 1 : 0;        // clamp pad (never consumed)
        ydW[sp * 64 + cc] = make_uint4(pkf16(b0[0], b0[SPD]),
                                       pkf16(b0[2*SPD], b0[3*SPD]),
                                       pkf16(b0[d], b0[SPD+d]),
                                       pkf16(b0[2*SPD+d], b0[3*SPD+d]));
        return;
    }
    id -= SPD * 64;
    if (id < N_TOT * 64) {                     // ---- B: z-stats
        int n  = id % N_TOT;                   // lanes = consecutive n -> coalesced reads
        int cc = id / N_TOT;
        int ni = n / N1, nj = n - ni * N1;
        const float* base = yd + (cc * 4) * SPD + ni * HD + nj;
        float s = 0.f, sq = 0.f;
#pragma unroll
        for (int r = 0; r < 4; ++r)
#pragma unroll
            for (int i = 0; i < 3; ++i)
#pragma unroll
                for (int j = 0; j < 3; ++j) {
                    float v = base[r * SPD + i * HD + j];
                    s += v; sq += v * v;
                }
        float mu  = s * (1.f / 36.f);
        float var = (sq - 36.f * mu * mu) * (1.f / 35.f);
        zstP[n * 64 + cc] = pkf16(mu, rsqrtf(var + EPSF));
        return;
    }
    id -= N_TOT * 64;
    if (id >= CY * M_TOT) return;              // ---- C: y-stats
    int m  = id % M_TOT;                       // lanes = consecutive m -> coalesced reads
    int cc = id / M_TOT;
    int mi = m / M1, mj = m - mi * M1;
    const float* base = y + cc * (HY * HY) + mi * HY + mj;
    float s = 0.f, sq = 0.f;
#pragma unroll
    for (int i = 0; i < 3; ++i)
#pragma unroll
        for (int j = 0; j < 3; ++j) {
            float v = base[i * HY + j];
            s += v; sq += v * v;
        }
    float mu  = s * (1.f / 9.f);
    float var = (sq - 9.f * mu * mu) * (1.f / 8.f);
    ystP[m * 64 + cc] = pkf16(mu, sqrtf(var + EPSF));
}

// Tile body: wave = 2 x-adjacent quads at (y, x0) for NK consecutive k's (k0..k0+NK-1).
// ystP loads + patch union SHARED across the NK k's; zstP/yd per k; per-row staging
// keeps live VGPRs in the 4-waves/SIMD bucket. Results staged to lds rows
// [kk*128 + dy*64 + cc] at col (w*2+q)*2+dx.
template<int NK>
__device__ __forceinline__ void tile_run(
    int lane, int w, int k0, int y, int x0,
    const uint4* __restrict__ ydW, const unsigned* __restrict__ zstP,
    const unsigned* __restrict__ ystP, const int* __restrict__ idx,
    float* lds, float inv[2])
{
    f32x2 acc01[NK][2], acc23[NK][2];
    float bs[NK][2];
#pragma unroll
    for (int kk = 0; kk < NK; ++kk)
#pragma unroll
        for (int q = 0; q < 2; ++q) {
            acc01[kk][q].x = 0.f; acc01[kk][q].y = 0.f;
            acc23[kk][q].x = 0.f; acc23[kk][q].y = 0.f;
            bs[kk][q] = 0.f;
        }

    auto serve = [&](int kk, int q, unsigned lo, unsigned hi, float a, float b) {
        f32x2 am; am.x = a; am.y = a;
        acc01[kk][q] = __builtin_elementwise_fma(am, upk2(lo), acc01[kk][q]);
        acc23[kk][q] = __builtin_elementwise_fma(am, upk2(hi), acc23[kk][q]);
        bs[kk][q] += b;
    };

    if (y >= 2 && y <= M1 - 1 && x0 >= 2 && x0 <= M1 - 2) {
        inv[0] = inv[1] = 1.f / 9.f;
        int nn[NK][12];                        // wave-uniform -> SGPRs
        unsigned ysu[12];
#pragma unroll
        for (int p = 0; p < 12; ++p) {
            int m = (y - 2 + (p >> 2)) * M1 + (x0 - 2 + (p & 3));
#pragma unroll
            for (int kk = 0; kk < NK; ++kk) nn[kk][p] = idx[m * KK + k0 + kk];
            ysu[p] = ystP[m * 64 + lane];      // shared across k
        }
#pragma unroll
        for (int r = 0; r < 3; ++r) {
            int roff = (2 - r) * HD;
            // per-row, per-k: stat + yd loads (scalar-addressed), then compute
            unsigned zsu[NK][4];
            uint2 v0[NK], v3[NK]; uint4 u1[NK], u2[NK];
#pragma unroll
            for (int kk = 0; kk < NK; ++kk) {
                int n0 = nn[kk][r*4+0], n1 = nn[kk][r*4+1];
                int n2 = nn[kk][r*4+2], n3 = nn[kk][r*4+3];
                int s0 = (n0 / N1) * HD + (n0 - (n0 / N1) * N1) + roff;
                int s1 = (n1 / N1) * HD + (n1 - (n1 / N1) * N1) + roff;
                int s2 = (n2 / N1) * HD + (n2 - (n2 / N1) * N1) + roff;
                int s3 = (n3 / N1) * HD + (n3 - (n3 / N1) * N1) + roff;
                v0[kk] = *(const uint2*)(ydW + (s0 + 2) * 64 + lane);  // A j=2
                u1[kk] = ydW[(s1 + 1) * 64 + lane];                    // A j=1 | B j=2
                u2[kk] = ydW[(s2 + 0) * 64 + lane];                    // A j=0 | B j=1
                v3[kk] = *(const uint2*)(ydW + (s3 + 0) * 64 + lane);  // B j=0
                zsu[kk][0] = zstP[n0 * 64 + lane];
                zsu[kk][1] = zstP[n1 * 64 + lane];
                zsu[kk][2] = zstP[n2 * 64 + lane];
                zsu[kk][3] = zstP[n3 * 64 + lane];
            }
#pragma unroll
            for (int kk = 0; kk < NK; ++kk) {
                float aa[4], bb[4];
#pragma unroll
                for (int c = 0; c < 4; ++c) {
                    f32x2 ys = upk2(ysu[r*4+c]), zs = upk2(zsu[kk][c]);
                    aa[c] = ys.y * zs.y;               // y_sd * inv_z_sd
                    bb[c] = fmaf(-zs.x, aa[c], ys.x);  // y_mu - z_mu*a
                }
                serve(kk, 0, v0[kk].x, v0[kk].y, aa[0], bb[0]);
                serve(kk, 0, u1[kk].x, u1[kk].y, aa[1], bb[1]);
                serve(kk, 1, u1[kk].z, u1[kk].w, aa[1], bb[1]);
                serve(kk, 0, u2[kk].x, u2[kk].y, aa[2], bb[2]);
                serve(kk, 1, u2[kk].z, u2[kk].w, aa[2], bb[2]);
                serve(kk, 1, v3[kk].x, v3[kk].y, aa[3], bb[3]);
            }
        }
    } else {
#pragma unroll
        for (int q = 0; q < 2; ++q) {
            int x = x0 + q;
            int milo = max(0, y - 2), mihi = min(M1 - 1, y);
            int mjlo = max(0, x - 2), mjhi = min(M1 - 1, x);
            inv[q] = 1.f / (float)((mihi - milo + 1) * (mjhi - mjlo + 1));
            for (int mi = milo; mi <= mihi; ++mi)
                for (int mj = mjlo; mj <= mjhi; ++mj) {
                    int m = mi * M1 + mj;
                    unsigned ysuv = ystP[m * 64 + lane];
#pragma unroll
                    for (int kk = 0; kk < NK; ++kk) {
                        int n = idx[m * KK + k0 + kk];  // uniform -> s_load
                        f32x2 ys = upk2(ysuv);
                        f32x2 zs = upk2(zstP[n * 64 + lane]);
                        float a = ys.y * zs.y;
                        float b = fmaf(-zs.x, a, ys.x);
                        int ni = n / N1;
                        int sp = ni * HD + (n - ni * N1) + (y - mi) * HD + (x - mj);
                        uint2 v = *(const uint2*)(ydW + sp * 64 + lane);
                        serve(kk, q, v.x, v.y, a, b);
                    }
                }
        }
    }

    // Stage: row = kk*128 + dy*64 + cc, col = (w*2+q)*2 + dx. Stride LP=17 -> free 2-way.
#pragma unroll
    for (int kk = 0; kk < NK; ++kk)
#pragma unroll
        for (int q = 0; q < 2; ++q) {
            float iv = inv[q];
            float bq = bs[kk][q];
            int col = (w * 2 + q) * 2;
            lds[((kk * 2 + 0) * CY + lane) * LP + col]     = (acc01[kk][q].x + bq) * iv;
            lds[((kk * 2 + 0) * CY + lane) * LP + col + 1] = (acc01[kk][q].y + bq) * iv;
            lds[((kk * 2 + 1) * CY + lane) * LP + col]     = (acc23[kk][q].x + bq) * iv;
            lds[((kk * 2 + 1) * CY + lane) * LP + col + 1] = (acc23[kk][q].y + bq) * iv;
        }
}

// Main: block = 4 waves (256 thr); wave = 2 quads x NK k's; NK=2 for kp<2 (k=0..3),
// NK=1 for kp=2 (k=4). Epilogue: LDS transpose -> full-line (64B) nt stores.
__global__ __launch_bounds__(256) void agg_kernel(
    const uint4* __restrict__ ydW, const unsigned* __restrict__ zstP,
    const unsigned* __restrict__ ystP, const int* __restrict__ idx,
    float* __restrict__ out)
{
    __shared__ float lds[256 * LP];            // 17,408 B

    int lane = threadIdx.x & 63;
    int w    = __builtin_amdgcn_readfirstlane(threadIdx.x >> 6);  // 0..3
    int bid  = blockIdx.x;                     // 0..2399
    int wg   = (bid & 7) * 300 + (bid >> 3);   // bijective XCD swizzle (2400 % 8 == 0)
    int kp   = wg / 800;                       // 0,1 -> NK=2; 2 -> NK=1
    int rem  = wg - kp * 800;
    int y    = rem / 10;                       // quad row 0..79
    int xb   = rem - y * 10;                   // x block 0..9 (16 X pixels)
    int x0   = xb * 8 + w * 2;                 // quad A col; quad B = x0+1
    int k0   = kp * 2;

    float inv[2];
    int nk;
    if (kp < 2) {
        tile_run<2>(lane, w, k0, y, x0, ydW, zstP, ystP, idx, lds, inv);
        nk = 2;
    } else {
        tile_run<1>(lane, w, k0, y, x0, ydW, zstP, ystP, idx, lds, inv);
        nk = 1;
    }

    __syncthreads();

    // Drain: nk*128 rows x 16 cols; each 16-lane group writes one FULL 64B line (nt).
    int qg = lane >> 4;                        // 0..3
    int xi = lane & 15;                        // 0..15
    int X0 = xb * 16, Y0 = 2 * y;
    for (int t = 0; t < nk * 8; ++t) {
        int row = t * 16 + w * 4 + qg;         // 0..nk*128-1
        float v = lds[row * LP + xi];
        int kk = row >> 7, dy = (row >> 6) & 1, cc = row & 63;
        __builtin_nontemporal_store(v,
            out + (((size_t)((k0 + kk) * CY + cc) * HS + (Y0 + dy)) * HS + X0 + xi));
    }
}

extern "C" void kernel_launch(void* const* d_in, const int* in_sizes, int n_in,
                              void* d_out, int out_size, void* d_ws, size_t ws_size,
                              hipStream_t stream) {
    const float* y   = (const float*)d_in[0];
    const float* yd  = (const float*)d_in[1];
    const int*   idx = (const int*)d_in[2];
    float* out = (float*)d_out;

    char* ws = (char*)d_ws;
    uint4*    ydW  = (uint4*)ws;                             // 1,638,400 B
    unsigned* zstP = (unsigned*)(ws + 1638400);              //   369,664 B
    unsigned* ystP = (unsigned*)(ws + 2008064);              // 1,557,504 B

    int pre_total = SPD * 64 + N_TOT * 64 + CY * M_TOT;      // 584,192 -> 2283 blocks
    pre_kernel<<<(pre_total + 255) / 256, 256, 0, stream>>>(y, yd, ydW, zstP, ystP);
    agg_kernel<<<3 * 800, 256, 0, stream>>>(ydW, zstP, ystP, idx, out);
}

// Round 17
// 32.429 us; speedup vs baseline: 1.2361x; 1.0520x over previous
//
#include <hip/hip_runtime.h>
#include <hip/hip_fp16.h>
#include <string.h>

// Problem constants (SCALE=2, K=5, PATCH=3, STRIDE=1)
#define CY     64           // y channels
#define HY     80           // y spatial
#define HD     40           // yd spatial
#define SPD    (HD*HD)      // 1600
#define M1     78           // query patch grid dim
#define N1     38           // matched patch grid dim
#define M_TOT  (M1*M1)      // 6084
#define N_TOT  (N1*N1)      // 1444
#define KK     5
#define HS     160          // output spatial
#define EPSF   1e-5f
#define LP     17           // LDS row pitch (floats) for 16-col epilogue: 2-way max (free)

typedef float f32x2 __attribute__((ext_vector_type(2)));

__device__ __forceinline__ unsigned pkf16(float a, float b) {
    __half2 h = __floats2half2_rn(a, b);
    unsigned u; memcpy(&u, &h, 4); return u;
}
__device__ __forceinline__ f32x2 upk2(unsigned u) {
    __half2 h; memcpy(&h, &u, 4);
    float2 f = __half22float2(h);
    f32x2 r; r.x = f.x; r.y = f.y; return r;
}

// Fused pre-pass, partitioned by flat thread id (all parts independent):
//  A: yd -> ydW[sp][cc] = uint4{ f16x4 @ sp, f16x4 @ sp+1 }  (dup-pair layout)
//  B: zstP[n][cc] = pack(mu, 1/sd) over 36 elems
//  C: ystP[m][cc] = pack(mu, sd) over 9 elems
__global__ __launch_bounds__(256) void pre_kernel(const float* __restrict__ y,
                                                  const float* __restrict__ yd,
                                                  uint4* __restrict__ ydW,
                                                  unsigned* __restrict__ zstP,
                                                  unsigned* __restrict__ ystP) {
    int id = blockIdx.x * 256 + threadIdx.x;
    if (id < SPD * 64) {                       // ---- A: transpose (coalesced writes)
        int cc = id & 63, sp = id >> 6;
        const float* b0 = yd + (cc * 4) * SPD + sp;
        int d = (sp < SPD - 1) ? 1 : 0;        // clamp pad (never consumed)
        ydW[sp * 64 + cc] = make_uint4(pkf16(b0[0], b0[SPD]),
                                       pkf16(b0[2*SPD], b0[3*SPD]),
                                       pkf16(b0[d], b0[SPD+d]),
                                       pkf16(b0[2*SPD+d], b0[3*SPD+d]));
        return;
    }
    id -= SPD * 64;
    if (id < N_TOT * 64) {                     // ---- B: z-stats
        int n  = id % N_TOT;                   // lanes = consecutive n -> coalesced reads
        int cc = id / N_TOT;
        int ni = n / N1, nj = n - ni * N1;
        const float* base = yd + (cc * 4) * SPD + ni * HD + nj;
        float s = 0.f, sq = 0.f;
#pragma unroll
        for (int r = 0; r < 4; ++r)
#pragma unroll
            for (int i = 0; i < 3; ++i)
#pragma unroll
                for (int j = 0; j < 3; ++j) {
                    float v = base[r * SPD + i * HD + j];
                    s += v; sq += v * v;
                }
        float mu  = s * (1.f / 36.f);
        float var = (sq - 36.f * mu * mu) * (1.f / 35.f);
        zstP[n * 64 + cc] = pkf16(mu, rsqrtf(var + EPSF));
        return;
    }
    id -= N_TOT * 64;
    if (id >= CY * M_TOT) return;              // ---- C: y-stats
    int m  = id % M_TOT;                       // lanes = consecutive m -> coalesced reads
    int cc = id / M_TOT;
    int mi = m / M1, mj = m - mi * M1;
    const float* base = y + cc * (HY * HY) + mi * HY + mj;
    float s = 0.f, sq = 0.f;
#pragma unroll
    for (int i = 0; i < 3; ++i)
#pragma unroll
        for (int j = 0; j < 3; ++j) {
            float v = base[i * HY + j];
            s += v; sq += v * v;
        }
    float mu  = s * (1.f / 9.f);
    float var = (sq - 9.f * mu * mu) * (1.f / 8.f);
    ystP[m * 64 + cc] = pkf16(mu, sqrtf(var + EPSF));
}

// Main: block = 4 waves (256 threads); wave = TWO x-adjacent 2x2 quads at one (k, quad-row y),
// lanes = cc. Coef computed INLINE per patch (uniform idx s_load -> stats wave-loads -> (a,b));
// 12 yd issues (2x uint4 + 2x uint2 per row), f32x2 pk-fma accumulators.
// Epilogue: LDS transpose over 16-pixel X span -> full-line (64B) non-temporal stores.
__global__ __launch_bounds__(256) void agg_kernel(
    const uint4* __restrict__ ydW, const unsigned* __restrict__ zstP,
    const unsigned* __restrict__ ystP, const int* __restrict__ idx,
    float* __restrict__ out)
{
    __shared__ float lds[128 * LP];            // 8,704 B

    int lane = threadIdx.x & 63;
    int w    = __builtin_amdgcn_readfirstlane(threadIdx.x >> 6);  // 0..3
    int bid  = blockIdx.x;                     // 0..3999
    int wg   = (bid & 7) * 500 + (bid >> 3);   // bijective XCD swizzle (4000 % 8 == 0)
    int k    = wg / 800;
    int rem  = wg - k * 800;
    int y    = rem / 10;                       // quad row 0..79
    int xb   = rem - y * 10;                   // x block 0..9 (16 X pixels)
    int x0   = xb * 8 + w * 2;                 // quad A col; quad B = x0+1

    f32x2 acc01[2] = {{0.f,0.f},{0.f,0.f}};    // dy0 row (r0,r1), quads A,B
    f32x2 acc23[2] = {{0.f,0.f},{0.f,0.f}};    // dy1 row (r2,r3)
    float bs[2] = {0.f, 0.f};
    float inv0, inv1;

    auto serve = [&](f32x2& a01, f32x2& a23, float& bsum,
                     unsigned lo, unsigned hi, float a, float b) {
        f32x2 am; am.x = a; am.y = a;
        a01 = __builtin_elementwise_fma(am, upk2(lo), a01);
        a23 = __builtin_elementwise_fma(am, upk2(hi), a23);
        bsum += b;
    };

    if (y >= 2 && y <= M1 - 1 && x0 >= 2 && x0 <= M1 - 2) {
        inv0 = inv1 = 1.f / 9.f;
        unsigned ysu[12], zsu[12];
        int nn[12];
#pragma unroll
        for (int p = 0; p < 12; ++p) {         // all independent, issued up front
            int m = (y - 2 + (p >> 2)) * M1 + (x0 - 2 + (p & 3));
            nn[p]  = idx[m * KK + k];          // uniform -> s_load
            ysu[p] = ystP[m * 64 + lane];
        }
#pragma unroll
        for (int p = 0; p < 12; ++p)
            zsu[p] = zstP[nn[p] * 64 + lane];
        float aa[12], bb[12];
        int spb[12];
#pragma unroll
        for (int p = 0; p < 12; ++p) {
            f32x2 ys = upk2(ysu[p]), zs = upk2(zsu[p]);
            aa[p] = ys.y * zs.y;               // y_sd * inv_z_sd
            bb[p] = fmaf(-zs.x, aa[p], ys.x);  // y_mu - z_mu*a
            int n = nn[p], ni = n / N1;        // scalar arithmetic
            spb[p] = ni * HD + (n - ni * N1);
        }
#pragma unroll
        for (int r = 0; r < 3; ++r) {
            int roff = (2 - r) * HD;
            int s0 = spb[r*4+0] + roff, s1 = spb[r*4+1] + roff;
            int s2 = spb[r*4+2] + roff, s3 = spb[r*4+3] + roff;
            uint2 v0 = *(const uint2*)(ydW + (s0 + 2) * 64 + lane);  // A j=2
            uint4 v1 = ydW[(s1 + 1) * 64 + lane];                    // A j=1 | B j=2
            uint4 v2 = ydW[(s2 + 0) * 64 + lane];                    // A j=0 | B j=1
            uint2 v3 = *(const uint2*)(ydW + (s3 + 0) * 64 + lane);  // B j=0
            serve(acc01[0], acc23[0], bs[0], v0.x, v0.y, aa[r*4+0], bb[r*4+0]);
            serve(acc01[0], acc23[0], bs[0], v1.x, v1.y, aa[r*4+1], bb[r*4+1]);
            serve(acc01[1], acc23[1], bs[1], v1.z, v1.w, aa[r*4+1], bb[r*4+1]);
            serve(acc01[0], acc23[0], bs[0], v2.x, v2.y, aa[r*4+2], bb[r*4+2]);
            serve(acc01[1], acc23[1], bs[1], v2.z, v2.w, aa[r*4+2], bb[r*4+2]);
            serve(acc01[1], acc23[1], bs[1], v3.x, v3.y, aa[r*4+3], bb[r*4+3]);
        }
    } else {
#pragma unroll
        for (int q = 0; q < 2; ++q) {
            int x = x0 + q;
            int milo = max(0, y - 2), mihi = min(M1 - 1, y);
            int mjlo = max(0, x - 2), mjhi = min(M1 - 1, x);
            float iv = 1.f / (float)((mihi - milo + 1) * (mjhi - mjlo + 1));
            if (q == 0) inv0 = iv; else inv1 = iv;
            for (int mi = milo; mi <= mihi; ++mi)
                for (int mj = mjlo; mj <= mjhi; ++mj) {
                    int m = mi * M1 + mj;
                    int n = idx[m * KK + k];   // uniform -> s_load
                    f32x2 ys = upk2(ystP[m * 64 + lane]);
                    f32x2 zs = upk2(zstP[n * 64 + lane]);
                    float a = ys.y * zs.y;
                    float b = fmaf(-zs.x, a, ys.x);
                    int ni = n / N1;
                    int sp = ni * HD + (n - ni * N1) + (y - mi) * HD + (x - mj);
                    uint2 v = *(const uint2*)(ydW + sp * 64 + lane);
                    if (q == 0) serve(acc01[0], acc23[0], bs[0], v.x, v.y, a, b);
                    else        serve(acc01[1], acc23[1], bs[1], v.x, v.y, a, b);
                }
        }
    }

    // Stage: row = dy*64 + cc (128 rows), col = (w*2+q)*2 + dx (16 cols). Stride LP=17 -> free 2-way.
#pragma unroll
    for (int q = 0; q < 2; ++q) {
        float iv = q ? inv1 : inv0;
        float bq = bs[q];
        int col = (w * 2 + q) * 2;
        lds[(0 * CY + lane) * LP + col]     = (acc01[q].x + bq) * iv;
        lds[(0 * CY + lane) * LP + col + 1] = (acc01[q].y + bq) * iv;
        lds[(1 * CY + lane) * LP + col]     = (acc23[q].x + bq) * iv;
        lds[(1 * CY + lane) * LP + col + 1] = (acc23[q].y + bq) * iv;
    }

    __syncthreads();

    // Drain: 128 rows x 16 cols; each 16-lane group writes one FULL 64B line (non-temporal).
    int q  = lane >> 4;                        // 0..3
    int xi = lane & 15;                        // 0..15
    int X0 = xb * 16, Y0 = 2 * y;
#pragma unroll
    for (int t = 0; t < 8; ++t) {
        int row = t * 16 + w * 4 + q;          // 0..127
        float v = lds[row * LP + xi];
        int dy = row >> 6, cc = row & 63;
        __builtin_nontemporal_store(v,
            out + (((size_t)(k * CY + cc) * HS + (Y0 + dy)) * HS + X0 + xi));
    }
}

extern "C" void kernel_launch(void* const* d_in, const int* in_sizes, int n_in,
                              void* d_out, int out_size, void* d_ws, size_t ws_size,
                              hipStream_t stream) {
    const float* y   = (const float*)d_in[0];
    const float* yd  = (const float*)d_in[1];
    const int*   idx = (const int*)d_in[2];
    float* out = (float*)d_out;

    char* ws = (char*)d_ws;
    uint4*    ydW  = (uint4*)ws;                             // 1,638,400 B
    unsigned* zstP = (unsigned*)(ws + 1638400);              //   369,664 B
    unsigned* ystP = (unsigned*)(ws + 2008064);              // 1,557,504 B

    int pre_total = SPD * 64 + N_TOT * 64 + CY * M_TOT;      // 584,192 -> 2283 blocks
    pre_kernel<<<(pre_total + 255) / 256, 256, 0, stream>>>(y, yd, ydW, zstP, ystP);
    agg_kernel<<<KK * 800, 256, 0, stream>>>(ydW, zstP, ystP, idx, out);
}